// Round 6
// baseline (206.502 us; speedup 1.0000x reference)
//
#include <hip/hip_runtime.h>
#include <math.h>

// Problem constants (B=16, H=512, W=512, fp32 in/out)
#define BB 16
#define HH 512
#define WW 512
#define NPIX (BB*HH*WW)   // 4194304
#define NROWS (BB*HH)     // 8192
#define NWORDS 16         // 512 rows / 32 bits
#define PADK 512          // pad each side of the horizontal LDS row

// ---------------------------------------------------------------------------
// Kernel A: build column bitmasks + per-column nearest-set-bit tables.
// 256 blocks x 512 threads: block = (b, 32-col tile), thread owns one
// (word k, col c). Wave 0 does the suffix scan (un), wave 1 the prefix (dn):
//   un[b][k][w]   = abs pos of first set bit >= 32k     (slot 16 = +16000)
//   dn[b][k+1][w] = abs pos of last  set bit <= 32k+31  (slot 0  = -16000)
// Also zeroes the completion counter used by the fused finalize.
// ---------------------------------------------------------------------------
__global__ __launch_bounds__(512) void build_kernel(
    const float* __restrict__ tg, unsigned int* __restrict__ mask,
    short* __restrict__ un_s, short* __restrict__ dn_s,
    unsigned int* __restrict__ counter) {
  __shared__ unsigned int smask[NWORDS][32];
  int wt = blockIdx.x & 15;          // 16 col-tiles of 32
  int b  = blockIdx.x >> 4;
  int c  = threadIdx.x & 31;
  int k  = threadIdx.x >> 5;         // 0..15
  int w  = (wt << 5) + c;
  if (blockIdx.x == 0 && threadIdx.x == 0) *counter = 0;
  const float* p = tg + ((size_t)(b * HH + (k << 5))) * WW + w;
  unsigned int word = 0;
  #pragma unroll
  for (int r = 0; r < 32; ++r)
    word |= (p[(size_t)r * WW] > 0.f ? 1u : 0u) << r;
  smask[k][c] = word;
  mask[(b * NWORDS + k) * WW + w] = word;
  __syncthreads();
  int t = threadIdx.x;
  if (t < 32) {                      // wave 0: suffix scan (first set >= 32k)
    int wcol = (wt << 5) + t;
    int cur = 16000;
    un_s[(b * 17 + 16) * WW + wcol] = (short)cur;
    #pragma unroll
    for (int k2 = NWORDS - 1; k2 >= 0; --k2) {
      unsigned int m = smask[k2][t];
      if (m) cur = (k2 << 5) + (int)__builtin_ctz(m);
      un_s[(b * 17 + k2) * WW + wcol] = (short)cur;
    }
  } else if (t >= 64 && t < 96) {    // wave 1: prefix scan (last set <= 32k+31)
    int tt = t - 64;
    int wcol = (wt << 5) + tt;
    int cur = -16000;
    dn_s[(b * 17 + 0) * WW + wcol] = (short)cur;
    #pragma unroll
    for (int k2 = 0; k2 < NWORDS; ++k2) {
      unsigned int m = smask[k2][tt];
      if (m) cur = (k2 << 5) + 31 - (int)__builtin_clz(m);
      dn_s[(b * 17 + k2 + 1) * WW + wcol] = (short)cur;
    }
  }
}

// ---------------------------------------------------------------------------
// Kernel B: fused vertical EDT (O(1)/px from tables) + horizontal min-plus
// (scalar stride-1 LDS scan, wave-uniform early exit) + loss + last-block
// finalize. One block per (b, h) row; thread owns columns {t, t+256}
// (stride-1 lanes -> conflict-free b32 LDS reads; NO indexed local arrays).
// All finite distance values are exact small ints in fp32.
// ---------------------------------------------------------------------------
__global__ __launch_bounds__(256) void rows_loss_kernel(
    const float* __restrict__ logits, const unsigned int* __restrict__ mask,
    const short* __restrict__ un_s, const short* __restrict__ dn_s,
    float* __restrict__ partials, unsigned int* __restrict__ counter,
    float* __restrict__ out) {
  __shared__ float s[PADK + WW + PADK];
  __shared__ float wsum[4][4];
  __shared__ int lastflag;

  int row = blockIdx.x;             // b*HH + h
  int b = row >> 9, i = row & 511;
  size_t rowbase = (size_t)row * WW;
  int tid = threadIdx.x;

  // pads (never allowed to win the min)
  s[tid] = 3e12f; s[tid + 256] = 3e12f;
  s[PADK + WW + tid] = 3e12f; s[PADK + WW + 256 + tid] = 3e12f;

  int k0 = i >> 5, pos = i & 31;    // block-uniform
  unsigned int pmask_lo = (1u << pos) - 1u;       // bits < pos
  unsigned int pmask_le = pmask_lo | (1u << pos); // bits <= pos
  const unsigned int* mrow = mask + (size_t)(b * NWORDS + k0) * WW;
  const short* unrow = un_s + (size_t)(b * 17 + k0 + 1) * WW;  // first set >= 32(k0+1)
  const short* dnrow = dn_s + (size_t)(b * 17 + k0) * WW;      // last set <= 32(k0-1)+31
  float tval[2];

  #pragma unroll
  for (int k2 = 0; k2 < 2; ++k2) {
    int w = tid + (k2 << 8);
    unsigned int m0 = mrow[w];
    int un_next = unrow[w];
    int dn_prev = dnrow[w];
    unsigned int upm  = m0 & ~pmask_lo;   // bits >= pos
    unsigned int lowm = m0 & pmask_le;    // bits <= pos
    int up  = upm  ? ((k0 << 5) + (int)__builtin_ctz(upm))       : un_next;
    int dnv = lowm ? ((k0 << 5) + 31 - (int)__builtin_clz(lowm)) : dn_prev;
    int bestv = min(up - i, i - dnv);
    tval[k2] = (up == i) ? 1.f : 0.f;     // bit i set iff nearest-up is i
    s[PADK + w] = (bestv > 511) ? 1e12f : (float)(bestv * bestv);
  }
  __syncthreads();

  float acc_p = 0.f, acc_t = 0.f, acc_pt = 0.f, acc_pen = 0.f;

  #pragma unroll
  for (int k2 = 0; k2 < 2; ++k2) {
    int w = tid + (k2 << 8);
    float x = logits[rowbase + w];     // issue early, consumed after scan
    float best = s[PADK + w];
    for (int o0 = 1; o0 < WW; o0 += 8) {
      #pragma unroll
      for (int u = 0; u < 8; ++u) {
        int o = o0 + u;
        float cand = fminf(s[PADK + w - o], s[PADK + w + o]) + (float)(o * o);
        best = fminf(best, cand);      // unconditional: losers can't lower best
      }
      float nxt = (float)((o0 + 8) * (o0 + 8));
      if (__all(nxt >= best)) break;   // wave-uniform exit, post-chunk vote
    }
    float e = __expf(-x);
    float p = __builtin_amdgcn_rcpf(1.f + e);     // sigmoid, ~1e-7 rel err
    float t = tval[k2];
    // empty sample => best ~ 1e12 => reference forces weight 0 (has_fg)
    float wgt = (best > 1e9f)
                    ? 0.f
                    : (1.f - __expf(-__builtin_amdgcn_sqrtf(best) * 0.02f));
    acc_p  += p;
    acc_t  += t;
    acc_pt += p * t;
    acc_pen += wgt * p * (1.f - t);
  }

  // wave(64) shuffle reduce, then across the 4 waves via LDS
  #pragma unroll
  for (int off = 32; off; off >>= 1) {
    acc_p  += __shfl_down(acc_p,  off);
    acc_t  += __shfl_down(acc_t,  off);
    acc_pt += __shfl_down(acc_pt, off);
    acc_pen += __shfl_down(acc_pen, off);
  }
  int wave = tid >> 6, lane = tid & 63;
  if (lane == 0) {
    wsum[wave][0] = acc_p; wsum[wave][1] = acc_t;
    wsum[wave][2] = acc_pt; wsum[wave][3] = acc_pen;
  }
  __syncthreads();
  if (tid == 0) {
    float r0 = 0.f, r1 = 0.f, r2 = 0.f, r3 = 0.f;
    #pragma unroll
    for (int wv = 0; wv < 4; ++wv) {
      r0 += wsum[wv][0]; r1 += wsum[wv][1];
      r2 += wsum[wv][2]; r3 += wsum[wv][3];
    }
    partials[0 * NROWS + row] = r0;
    partials[1 * NROWS + row] = r1;
    partials[2 * NROWS + row] = r2;
    partials[3 * NROWS + row] = r3;
    __threadfence();                         // release partials
    unsigned int prev = atomicAdd(counter, 1u);
    lastflag = (prev == NROWS - 1) ? 1 : 0;
  }
  __syncthreads();

  // Last finished block reduces all partials and writes the scalar loss.
  if (lastflag) {
    __threadfence();                         // acquire other blocks' partials
    float a0 = 0.f, a1 = 0.f, a2 = 0.f, a3 = 0.f;
    for (int k = tid; k < NROWS; k += 256) {
      a0 += partials[0 * NROWS + k];
      a1 += partials[1 * NROWS + k];
      a2 += partials[2 * NROWS + k];
      a3 += partials[3 * NROWS + k];
    }
    #pragma unroll
    for (int off = 32; off; off >>= 1) {
      a0 += __shfl_down(a0, off);
      a1 += __shfl_down(a1, off);
      a2 += __shfl_down(a2, off);
      a3 += __shfl_down(a3, off);
    }
    if (lane == 0) {
      wsum[wave][0] = a0; wsum[wave][1] = a1;
      wsum[wave][2] = a2; wsum[wave][3] = a3;
    }
    __syncthreads();
    if (tid == 0) {
      float sp = 0.f, st = 0.f, inter = 0.f, pen = 0.f;
      #pragma unroll
      for (int wv = 0; wv < 4; ++wv) {
        sp += wsum[wv][0]; st += wsum[wv][1];
        inter += wsum[wv][2]; pen += wsum[wv][3];
      }
      float uni = sp + st - inter;
      float iou_loss = 1.f - (inter + 1e-6f) / (uni + 1e-6f);
      float penalty = pen / (float)NPIX;
      out[0] = iou_loss + 0.5f * penalty;
    }
  }
}

extern "C" void kernel_launch(void* const* d_in, const int* in_sizes, int n_in,
                              void* d_out, int out_size, void* d_ws, size_t ws_size,
                              hipStream_t stream) {
  const float* logits = (const float*)d_in[0];
  const float* tg     = (const float*)d_in[1];
  char* base = (char*)d_ws;
  unsigned int* mask = (unsigned int*)base;               // 512 KB
  short* un_s = (short*)(base + 524288);                  // 16*17*512 shorts
  short* dn_s = (short*)(base + 802816);
  float* partials = (float*)(base + 1081344);             // 128 KB
  unsigned int* counter = (unsigned int*)(base + 1212416);
  float* out = (float*)d_out;

  hipLaunchKernelGGL(build_kernel, dim3(BB * 16), dim3(512), 0, stream,
                     tg, mask, un_s, dn_s, counter);
  hipLaunchKernelGGL(rows_loss_kernel, dim3(NROWS), dim3(256), 0, stream,
                     logits, mask, un_s, dn_s, partials, counter, out);
}

// Round 7
// 40.490 us; speedup vs baseline: 5.1001x; 5.1001x over previous
//
#include <hip/hip_runtime.h>
#include <math.h>

// Problem constants (B=16, H=512, W=512, fp32 in/out)
#define BB 16
#define HH 512
#define WW 512
#define NPIX (BB*HH*WW)   // 4194304
#define NROWS (BB*HH)     // 8192
#define NWORDS 16         // 512 rows / 32 bits
#define PADK 512          // pad each side of the horizontal LDS row

// ---------------------------------------------------------------------------
// Kernel A: build column bitmasks + per-column nearest-set-bit tables.
// 256 blocks x 512 threads: block = (b, 32-col tile), thread owns one
// (word k, col c). Wave 0 does the suffix scan (un), wave 1 the prefix (dn):
//   un[b][k][w]   = abs pos of first set bit >= 32k     (slot 16 = +16000)
//   dn[b][k+1][w] = abs pos of last  set bit <= 32k+31  (slot 0  = -16000)
// No atomics, no fences.
// ---------------------------------------------------------------------------
__global__ __launch_bounds__(512) void build_kernel(
    const float* __restrict__ tg, unsigned int* __restrict__ mask,
    short* __restrict__ un_s, short* __restrict__ dn_s) {
  __shared__ unsigned int smask[NWORDS][32];
  int wt = blockIdx.x & 15;          // 16 col-tiles of 32
  int b  = blockIdx.x >> 4;
  int c  = threadIdx.x & 31;
  int k  = threadIdx.x >> 5;         // 0..15
  int w  = (wt << 5) + c;
  const float* p = tg + ((size_t)(b * HH + (k << 5))) * WW + w;
  unsigned int word = 0;
  #pragma unroll
  for (int r = 0; r < 32; ++r)
    word |= (p[(size_t)r * WW] > 0.f ? 1u : 0u) << r;
  smask[k][c] = word;
  mask[(b * NWORDS + k) * WW + w] = word;
  __syncthreads();
  int t = threadIdx.x;
  if (t < 32) {                      // wave 0: suffix scan (first set >= 32k)
    int wcol = (wt << 5) + t;
    int cur = 16000;
    un_s[(b * 17 + 16) * WW + wcol] = (short)cur;
    #pragma unroll
    for (int k2 = NWORDS - 1; k2 >= 0; --k2) {
      unsigned int m = smask[k2][t];
      if (m) cur = (k2 << 5) + (int)__builtin_ctz(m);
      un_s[(b * 17 + k2) * WW + wcol] = (short)cur;
    }
  } else if (t >= 64 && t < 96) {    // wave 1: prefix scan (last set <= 32k+31)
    int tt = t - 64;
    int wcol = (wt << 5) + tt;
    int cur = -16000;
    dn_s[(b * 17 + 0) * WW + wcol] = (short)cur;
    #pragma unroll
    for (int k2 = 0; k2 < NWORDS; ++k2) {
      unsigned int m = smask[k2][tt];
      if (m) cur = (k2 << 5) + 31 - (int)__builtin_clz(m);
      dn_s[(b * 17 + k2 + 1) * WW + wcol] = (short)cur;
    }
  }
}

// ---------------------------------------------------------------------------
// Kernel B: VERBATIM the R4-proven rows kernel (45.6us-class, VGPR 32,
// VALUBusy ~90%). Fused vertical EDT (O(1)/px from tables) + horizontal
// min-plus (scalar stride-1 LDS scan, pre-chunk wave-uniform early exit) +
// loss partials. One block per (b, h) row; thread owns columns {t, t+256}.
// No atomics, no fences, no device-scope tail.
// ---------------------------------------------------------------------------
__global__ __launch_bounds__(256) void rows_loss_kernel(
    const float* __restrict__ logits, const unsigned int* __restrict__ mask,
    const short* __restrict__ un_s, const short* __restrict__ dn_s,
    float* __restrict__ partials) {
  __shared__ float s[PADK + WW + PADK];
  __shared__ float wsum[4][4];

  int row = blockIdx.x;             // b*HH + h
  int b = row >> 9, i = row & 511;  // h index within image
  size_t rowbase = (size_t)row * WW;
  int tid = threadIdx.x;

  // pads (never allowed to win the min)
  s[tid] = 3e12f; s[tid + 256] = 3e12f;
  s[PADK + WW + tid] = 3e12f; s[PADK + WW + 256 + tid] = 3e12f;

  int k0 = i >> 5, pos = i & 31;    // block-uniform
  unsigned int pmask_lo = (1u << pos) - 1u;       // bits < pos
  unsigned int pmask_le = pmask_lo | (1u << pos); // bits <= pos
  const unsigned int* mrow = mask + (size_t)(b * NWORDS + k0) * WW;
  const short* unrow = un_s + (size_t)(b * 17 + k0 + 1) * WW;  // first set >= 32(k0+1)
  const short* dnrow = dn_s + (size_t)(b * 17 + k0) * WW;      // last set <= 32(k0-1)+31
  float tval[2];

  #pragma unroll
  for (int k2 = 0; k2 < 2; ++k2) {
    int w = tid + (k2 << 8);
    unsigned int m0 = mrow[w];
    int un_next = unrow[w];
    int dn_prev = dnrow[w];
    unsigned int upm  = m0 & ~pmask_lo;   // bits >= pos
    unsigned int lowm = m0 & pmask_le;    // bits <= pos
    int up  = upm  ? ((k0 << 5) + (int)__builtin_ctz(upm))       : un_next;
    int dnv = lowm ? ((k0 << 5) + 31 - (int)__builtin_clz(lowm)) : dn_prev;
    int bestv = min(up - i, i - dnv);
    tval[k2] = (up == i) ? 1.f : 0.f;     // bit i set iff nearest-up is i itself
    s[PADK + w] = (bestv > 511) ? 1e12f : (float)(bestv * bestv);
  }
  __syncthreads();

  float acc_p = 0.f, acc_t = 0.f, acc_pt = 0.f, acc_pen = 0.f;

  #pragma unroll
  for (int k2 = 0; k2 < 2; ++k2) {
    int w = tid + (k2 << 8);
    float x = logits[rowbase + w];     // issue early, consumed after scan
    float best = s[PADK + w];
    for (int o0 = 1; o0 < WW; o0 += 8) {
      if (__all((float)(o0 * o0) >= best)) break;  // wave-uniform exit
      #pragma unroll
      for (int u = 0; u < 8; ++u) {
        int o = o0 + u;
        float cand = fminf(s[PADK + w - o], s[PADK + w + o]) + (float)(o * o);
        best = fminf(best, cand);      // unconditional: losers can't lower best
      }
    }
    float e = __expf(-x);
    float p = __builtin_amdgcn_rcpf(1.f + e);          // sigmoid, ~1e-7 rel err
    float t = tval[k2];
    // empty sample => best ~ 1e12 => reference forces weight 0 (has_fg)
    float wgt = (best > 1e9f)
                    ? 0.f
                    : (1.f - __expf(-__builtin_amdgcn_sqrtf(best) * 0.02f));
    acc_p  += p;
    acc_t  += t;
    acc_pt += p * t;
    acc_pen += wgt * p * (1.f - t);
  }

  // wave(64) shuffle reduce, then across the 4 waves via LDS
  #pragma unroll
  for (int off = 32; off; off >>= 1) {
    acc_p  += __shfl_down(acc_p,  off);
    acc_t  += __shfl_down(acc_t,  off);
    acc_pt += __shfl_down(acc_pt, off);
    acc_pen += __shfl_down(acc_pen, off);
  }
  int wave = tid >> 6, lane = tid & 63;
  if (lane == 0) {
    wsum[wave][0] = acc_p; wsum[wave][1] = acc_t;
    wsum[wave][2] = acc_pt; wsum[wave][3] = acc_pen;
  }
  __syncthreads();
  if (tid == 0) {
    float r0 = 0.f, r1 = 0.f, r2 = 0.f, r3 = 0.f;
    #pragma unroll
    for (int wv = 0; wv < 4; ++wv) {
      r0 += wsum[wv][0]; r1 += wsum[wv][1];
      r2 += wsum[wv][2]; r3 += wsum[wv][3];
    }
    partials[0 * NROWS + row] = r0;
    partials[1 * NROWS + row] = r1;
    partials[2 * NROWS + row] = r2;
    partials[3 * NROWS + row] = r3;
  }
}

// ---------------------------------------------------------------------------
// Kernel C: deterministic final reduce of 8192x4 partials + scalar loss.
// ---------------------------------------------------------------------------
__global__ __launch_bounds__(256) void finalize_kernel(
    const float* __restrict__ partials, float* __restrict__ out) {
  __shared__ float wsum[4][4];
  int tid = threadIdx.x;
  float a0 = 0.f, a1 = 0.f, a2 = 0.f, a3 = 0.f;
  for (int k = tid; k < NROWS; k += 256) {
    a0 += partials[0 * NROWS + k];
    a1 += partials[1 * NROWS + k];
    a2 += partials[2 * NROWS + k];
    a3 += partials[3 * NROWS + k];
  }
  #pragma unroll
  for (int off = 32; off; off >>= 1) {
    a0 += __shfl_down(a0, off);
    a1 += __shfl_down(a1, off);
    a2 += __shfl_down(a2, off);
    a3 += __shfl_down(a3, off);
  }
  int wave = tid >> 6, lane = tid & 63;
  if (lane == 0) {
    wsum[wave][0] = a0; wsum[wave][1] = a1;
    wsum[wave][2] = a2; wsum[wave][3] = a3;
  }
  __syncthreads();
  if (tid == 0) {
    float sp = 0.f, st = 0.f, inter = 0.f, pen = 0.f;
    #pragma unroll
    for (int wv = 0; wv < 4; ++wv) {
      sp += wsum[wv][0]; st += wsum[wv][1];
      inter += wsum[wv][2]; pen += wsum[wv][3];
    }
    float uni = sp + st - inter;
    float iou_loss = 1.f - (inter + 1e-6f) / (uni + 1e-6f);
    float penalty = pen / (float)NPIX;
    out[0] = iou_loss + 0.5f * penalty;
  }
}

extern "C" void kernel_launch(void* const* d_in, const int* in_sizes, int n_in,
                              void* d_out, int out_size, void* d_ws, size_t ws_size,
                              hipStream_t stream) {
  const float* logits = (const float*)d_in[0];
  const float* tg     = (const float*)d_in[1];
  char* base = (char*)d_ws;
  unsigned int* mask = (unsigned int*)base;               // 512 KB
  short* un_s = (short*)(base + 524288);                  // 16*17*512 shorts
  short* dn_s = (short*)(base + 802816);
  float* partials = (float*)(base + 1081344);             // 128 KB
  float* out = (float*)d_out;

  hipLaunchKernelGGL(build_kernel, dim3(BB * 16), dim3(512), 0, stream,
                     tg, mask, un_s, dn_s);
  hipLaunchKernelGGL(rows_loss_kernel, dim3(NROWS), dim3(256), 0, stream,
                     logits, mask, un_s, dn_s, partials);
  hipLaunchKernelGGL(finalize_kernel, dim3(1), dim3(256), 0, stream,
                     partials, out);
}

// Round 8
// 40.389 us; speedup vs baseline: 5.1128x; 1.0025x over previous
//
#include <hip/hip_runtime.h>
#include <math.h>

// Problem constants (B=16, H=512, W=512, fp32 in/out)
#define BB 16
#define HH 512
#define WW 512
#define NPIX (BB*HH*WW)   // 4194304
#define NROWS (BB*HH)     // 8192
#define NWORDS 16         // 512 rows / 32 bits
#define PADK 512          // pad each side of the horizontal LDS row

// ---------------------------------------------------------------------------
// Kernel A: build column bitmasks + per-column nearest-set-bit tables.
// 256 blocks x 512 threads: block = (b, 32-col tile), thread owns one
// (word k, col c). Wave 0 does the suffix scan (un), wave 1 the prefix (dn):
//   un[b][k][w]   = abs pos of first set bit >= 32k     (slot 16 = +16000)
//   dn[b][k+1][w] = abs pos of last  set bit <= 32k+31  (slot 0  = -16000)
// No atomics, no fences.
// ---------------------------------------------------------------------------
__global__ __launch_bounds__(512) void build_kernel(
    const float* __restrict__ tg, unsigned int* __restrict__ mask,
    short* __restrict__ un_s, short* __restrict__ dn_s) {
  __shared__ unsigned int smask[NWORDS][32];
  int wt = blockIdx.x & 15;          // 16 col-tiles of 32
  int b  = blockIdx.x >> 4;
  int c  = threadIdx.x & 31;
  int k  = threadIdx.x >> 5;         // 0..15
  int w  = (wt << 5) + c;
  const float* p = tg + ((size_t)(b * HH + (k << 5))) * WW + w;
  unsigned int word = 0;
  #pragma unroll
  for (int r = 0; r < 32; ++r)
    word |= (p[(size_t)r * WW] > 0.f ? 1u : 0u) << r;
  smask[k][c] = word;
  mask[(b * NWORDS + k) * WW + w] = word;
  __syncthreads();
  int t = threadIdx.x;
  if (t < 32) {                      // wave 0: suffix scan (first set >= 32k)
    int wcol = (wt << 5) + t;
    int cur = 16000;
    un_s[(b * 17 + 16) * WW + wcol] = (short)cur;
    #pragma unroll
    for (int k2 = NWORDS - 1; k2 >= 0; --k2) {
      unsigned int m = smask[k2][t];
      if (m) cur = (k2 << 5) + (int)__builtin_ctz(m);
      un_s[(b * 17 + k2) * WW + wcol] = (short)cur;
    }
  } else if (t >= 64 && t < 96) {    // wave 1: prefix scan (last set <= 32k+31)
    int tt = t - 64;
    int wcol = (wt << 5) + tt;
    int cur = -16000;
    dn_s[(b * 17 + 0) * WW + wcol] = (short)cur;
    #pragma unroll
    for (int k2 = 0; k2 < NWORDS; ++k2) {
      unsigned int m = smask[k2][tt];
      if (m) cur = (k2 << 5) + 31 - (int)__builtin_clz(m);
      dn_s[(b * 17 + k2 + 1) * WW + wcol] = (short)cur;
    }
  }
}

// ---------------------------------------------------------------------------
// Kernel B: VERBATIM the R4-proven rows kernel (45.6us-class, VGPR 32,
// VALUBusy ~90%). Fused vertical EDT (O(1)/px from tables) + horizontal
// min-plus (scalar stride-1 LDS scan, pre-chunk wave-uniform early exit) +
// loss partials. One block per (b, h) row; thread owns columns {t, t+256}.
// No atomics, no fences, no device-scope tail.
// ---------------------------------------------------------------------------
__global__ __launch_bounds__(256) void rows_loss_kernel(
    const float* __restrict__ logits, const unsigned int* __restrict__ mask,
    const short* __restrict__ un_s, const short* __restrict__ dn_s,
    float* __restrict__ partials) {
  __shared__ float s[PADK + WW + PADK];
  __shared__ float wsum[4][4];

  int row = blockIdx.x;             // b*HH + h
  int b = row >> 9, i = row & 511;  // h index within image
  size_t rowbase = (size_t)row * WW;
  int tid = threadIdx.x;

  // pads (never allowed to win the min)
  s[tid] = 3e12f; s[tid + 256] = 3e12f;
  s[PADK + WW + tid] = 3e12f; s[PADK + WW + 256 + tid] = 3e12f;

  int k0 = i >> 5, pos = i & 31;    // block-uniform
  unsigned int pmask_lo = (1u << pos) - 1u;       // bits < pos
  unsigned int pmask_le = pmask_lo | (1u << pos); // bits <= pos
  const unsigned int* mrow = mask + (size_t)(b * NWORDS + k0) * WW;
  const short* unrow = un_s + (size_t)(b * 17 + k0 + 1) * WW;  // first set >= 32(k0+1)
  const short* dnrow = dn_s + (size_t)(b * 17 + k0) * WW;      // last set <= 32(k0-1)+31
  float tval[2];

  #pragma unroll
  for (int k2 = 0; k2 < 2; ++k2) {
    int w = tid + (k2 << 8);
    unsigned int m0 = mrow[w];
    int un_next = unrow[w];
    int dn_prev = dnrow[w];
    unsigned int upm  = m0 & ~pmask_lo;   // bits >= pos
    unsigned int lowm = m0 & pmask_le;    // bits <= pos
    int up  = upm  ? ((k0 << 5) + (int)__builtin_ctz(upm))       : un_next;
    int dnv = lowm ? ((k0 << 5) + 31 - (int)__builtin_clz(lowm)) : dn_prev;
    int bestv = min(up - i, i - dnv);
    tval[k2] = (up == i) ? 1.f : 0.f;     // bit i set iff nearest-up is i itself
    s[PADK + w] = (bestv > 511) ? 1e12f : (float)(bestv * bestv);
  }
  __syncthreads();

  float acc_p = 0.f, acc_t = 0.f, acc_pt = 0.f, acc_pen = 0.f;

  #pragma unroll
  for (int k2 = 0; k2 < 2; ++k2) {
    int w = tid + (k2 << 8);
    float x = logits[rowbase + w];     // issue early, consumed after scan
    float best = s[PADK + w];
    for (int o0 = 1; o0 < WW; o0 += 8) {
      if (__all((float)(o0 * o0) >= best)) break;  // wave-uniform exit
      #pragma unroll
      for (int u = 0; u < 8; ++u) {
        int o = o0 + u;
        float cand = fminf(s[PADK + w - o], s[PADK + w + o]) + (float)(o * o);
        best = fminf(best, cand);      // unconditional: losers can't lower best
      }
    }
    float e = __expf(-x);
    float p = __builtin_amdgcn_rcpf(1.f + e);          // sigmoid, ~1e-7 rel err
    float t = tval[k2];
    // empty sample => best ~ 1e12 => reference forces weight 0 (has_fg)
    float wgt = (best > 1e9f)
                    ? 0.f
                    : (1.f - __expf(-__builtin_amdgcn_sqrtf(best) * 0.02f));
    acc_p  += p;
    acc_t  += t;
    acc_pt += p * t;
    acc_pen += wgt * p * (1.f - t);
  }

  // wave(64) shuffle reduce, then across the 4 waves via LDS
  #pragma unroll
  for (int off = 32; off; off >>= 1) {
    acc_p  += __shfl_down(acc_p,  off);
    acc_t  += __shfl_down(acc_t,  off);
    acc_pt += __shfl_down(acc_pt, off);
    acc_pen += __shfl_down(acc_pen, off);
  }
  int wave = tid >> 6, lane = tid & 63;
  if (lane == 0) {
    wsum[wave][0] = acc_p; wsum[wave][1] = acc_t;
    wsum[wave][2] = acc_pt; wsum[wave][3] = acc_pen;
  }
  __syncthreads();
  if (tid == 0) {
    float r0 = 0.f, r1 = 0.f, r2 = 0.f, r3 = 0.f;
    #pragma unroll
    for (int wv = 0; wv < 4; ++wv) {
      r0 += wsum[wv][0]; r1 += wsum[wv][1];
      r2 += wsum[wv][2]; r3 += wsum[wv][3];
    }
    partials[0 * NROWS + row] = r0;
    partials[1 * NROWS + row] = r1;
    partials[2 * NROWS + row] = r2;
    partials[3 * NROWS + row] = r3;
  }
}

// ---------------------------------------------------------------------------
// Kernel C: deterministic final reduce of 8192x4 partials + scalar loss.
// ---------------------------------------------------------------------------
__global__ __launch_bounds__(256) void finalize_kernel(
    const float* __restrict__ partials, float* __restrict__ out) {
  __shared__ float wsum[4][4];
  int tid = threadIdx.x;
  float a0 = 0.f, a1 = 0.f, a2 = 0.f, a3 = 0.f;
  for (int k = tid; k < NROWS; k += 256) {
    a0 += partials[0 * NROWS + k];
    a1 += partials[1 * NROWS + k];
    a2 += partials[2 * NROWS + k];
    a3 += partials[3 * NROWS + k];
  }
  #pragma unroll
  for (int off = 32; off; off >>= 1) {
    a0 += __shfl_down(a0, off);
    a1 += __shfl_down(a1, off);
    a2 += __shfl_down(a2, off);
    a3 += __shfl_down(a3, off);
  }
  int wave = tid >> 6, lane = tid & 63;
  if (lane == 0) {
    wsum[wave][0] = a0; wsum[wave][1] = a1;
    wsum[wave][2] = a2; wsum[wave][3] = a3;
  }
  __syncthreads();
  if (tid == 0) {
    float sp = 0.f, st = 0.f, inter = 0.f, pen = 0.f;
    #pragma unroll
    for (int wv = 0; wv < 4; ++wv) {
      sp += wsum[wv][0]; st += wsum[wv][1];
      inter += wsum[wv][2]; pen += wsum[wv][3];
    }
    float uni = sp + st - inter;
    float iou_loss = 1.f - (inter + 1e-6f) / (uni + 1e-6f);
    float penalty = pen / (float)NPIX;
    out[0] = iou_loss + 0.5f * penalty;
  }
}

extern "C" void kernel_launch(void* const* d_in, const int* in_sizes, int n_in,
                              void* d_out, int out_size, void* d_ws, size_t ws_size,
                              hipStream_t stream) {
  const float* logits = (const float*)d_in[0];
  const float* tg     = (const float*)d_in[1];
  char* base = (char*)d_ws;
  unsigned int* mask = (unsigned int*)base;               // 512 KB
  short* un_s = (short*)(base + 524288);                  // 16*17*512 shorts
  short* dn_s = (short*)(base + 802816);
  float* partials = (float*)(base + 1081344);             // 128 KB
  float* out = (float*)d_out;

  hipLaunchKernelGGL(build_kernel, dim3(BB * 16), dim3(512), 0, stream,
                     tg, mask, un_s, dn_s);
  hipLaunchKernelGGL(rows_loss_kernel, dim3(NROWS), dim3(256), 0, stream,
                     logits, mask, un_s, dn_s, partials);
  hipLaunchKernelGGL(finalize_kernel, dim3(1), dim3(256), 0, stream,
                     partials, out);
}

// Round 9
// 38.493 us; speedup vs baseline: 5.3647x; 1.0493x over previous
//
#include <hip/hip_runtime.h>
#include <math.h>

// Problem constants (B=16, H=512, W=512, fp32 in/out)
#define BB 16
#define HH 512
#define WW 512
#define NPIX (BB*HH*WW)   // 4194304
#define NROWS (BB*HH)     // 8192
#define NWORDS 16         // 512 rows / 32 bits
#define PADK 512          // pad each side of the horizontal LDS row

// ---------------------------------------------------------------------------
// Kernel A: build column bitmasks + per-column nearest-set-bit tables.
// 256 blocks x 512 threads: block = (b, 32-col tile), thread owns one
// (word k, col c). Wave 0 does the suffix scan (un), wave 1 the prefix (dn):
//   un[b][k][w]   = abs pos of first set bit >= 32k     (slot 16 = +16000)
//   dn[b][k+1][w] = abs pos of last  set bit <= 32k+31  (slot 0  = -16000)
// No atomics, no fences.
// ---------------------------------------------------------------------------
__global__ __launch_bounds__(512) void build_kernel(
    const float* __restrict__ tg, unsigned int* __restrict__ mask,
    short* __restrict__ un_s, short* __restrict__ dn_s) {
  __shared__ unsigned int smask[NWORDS][32];
  int wt = blockIdx.x & 15;          // 16 col-tiles of 32
  int b  = blockIdx.x >> 4;
  int c  = threadIdx.x & 31;
  int k  = threadIdx.x >> 5;         // 0..15
  int w  = (wt << 5) + c;
  const float* p = tg + ((size_t)(b * HH + (k << 5))) * WW + w;
  unsigned int word = 0;
  #pragma unroll
  for (int r = 0; r < 32; ++r)
    word |= (p[(size_t)r * WW] > 0.f ? 1u : 0u) << r;
  smask[k][c] = word;
  mask[(b * NWORDS + k) * WW + w] = word;
  __syncthreads();
  int t = threadIdx.x;
  if (t < 32) {                      // wave 0: suffix scan (first set >= 32k)
    int wcol = (wt << 5) + t;
    int cur = 16000;
    un_s[(b * 17 + 16) * WW + wcol] = (short)cur;
    #pragma unroll
    for (int k2 = NWORDS - 1; k2 >= 0; --k2) {
      unsigned int m = smask[k2][t];
      if (m) cur = (k2 << 5) + (int)__builtin_ctz(m);
      un_s[(b * 17 + k2) * WW + wcol] = (short)cur;
    }
  } else if (t >= 64 && t < 96) {    // wave 1: prefix scan (last set <= 32k+31)
    int tt = t - 64;
    int wcol = (wt << 5) + tt;
    int cur = -16000;
    dn_s[(b * 17 + 0) * WW + wcol] = (short)cur;
    #pragma unroll
    for (int k2 = 0; k2 < NWORDS; ++k2) {
      unsigned int m = smask[k2][tt];
      if (m) cur = (k2 << 5) + 31 - (int)__builtin_clz(m);
      dn_s[(b * 17 + k2 + 1) * WW + wcol] = (short)cur;
    }
  }
}

// ---------------------------------------------------------------------------
// Kernel B: fused vertical EDT (O(1)/px from tables) + horizontal min-plus
// + loss partials. One block per (b, h) row; thread owns ADJACENT columns
// {2t, 2t+1} so each 8-offset chunk shares two contiguous float2 windows
// (10 x ds_read_b64) between both pixels. All extraction uses NAMED float2
// registers with literal .x/.y accesses - nothing the compiler can demote
// to scratch. No atomics, no fences, no device-scope tail.
// All finite distance values are exact small ints in fp32.
// ---------------------------------------------------------------------------
__global__ __launch_bounds__(256) void rows_loss_kernel(
    const float* __restrict__ logits, const unsigned int* __restrict__ mask,
    const short* __restrict__ un_s, const short* __restrict__ dn_s,
    float* __restrict__ partials) {
  __shared__ __align__(16) float sraw[2 * PADK + WW];
  __shared__ float wsum[4][4];
  float* sA = sraw + PADK;

  int row = blockIdx.x;             // b*HH + h
  int b = row >> 9, i = row & 511;
  size_t rowbase = (size_t)row * WW;
  int tid = threadIdx.x;
  int w0 = tid << 1;                // even; owns w0 and w0+1

  // pads (never allowed to win the min)
  *(float2*)&sraw[w0] = make_float2(3e12f, 3e12f);
  *(float2*)&sraw[1024 + w0] = make_float2(3e12f, 3e12f);

  int k0 = i >> 5, pos = i & 31;    // block-uniform
  unsigned int pmask_lo = (1u << pos) - 1u;       // bits < pos
  unsigned int pmask_le = pmask_lo | (1u << pos); // bits <= pos
  const unsigned int* mrow = mask + (size_t)(b * NWORDS + k0) * WW;
  const short* unrow = un_s + (size_t)(b * 17 + k0 + 1) * WW;  // first set >= 32(k0+1)
  const short* dnrow = dn_s + (size_t)(b * 17 + k0) * WW;      // last set <= 32(k0-1)+31

  uint2 m2 = *(const uint2*)&mrow[w0];
  int un2 = *(const int*)&unrow[w0];
  int dn2 = *(const int*)&dnrow[w0];
  float2 xv = *(const float2*)&logits[rowbase + w0];

  // ---- vertical EDT, px0 ----
  unsigned int upm0  = m2.x & ~pmask_lo;
  unsigned int lowm0 = m2.x & pmask_le;
  int up0  = upm0  ? ((k0 << 5) + (int)__builtin_ctz(upm0))       : (int)(short)(un2 & 0xffff);
  int dnv0 = lowm0 ? ((k0 << 5) + 31 - (int)__builtin_clz(lowm0)) : (int)(short)(dn2 & 0xffff);
  int bv0 = min(up0 - i, i - dnv0);
  float tval0 = (up0 == i) ? 1.f : 0.f;
  float dv0 = (bv0 > 511) ? 1e12f : (float)(bv0 * bv0);
  // ---- vertical EDT, px1 ----
  unsigned int upm1  = m2.y & ~pmask_lo;
  unsigned int lowm1 = m2.y & pmask_le;
  int up1  = upm1  ? ((k0 << 5) + (int)__builtin_ctz(upm1))       : (int)(short)(un2 >> 16);
  int dnv1 = lowm1 ? ((k0 << 5) + 31 - (int)__builtin_clz(lowm1)) : (int)(short)(dn2 >> 16);
  int bv1 = min(up1 - i, i - dnv1);
  float tval1 = (up1 == i) ? 1.f : 0.f;
  float dv1 = (bv1 > 511) ? 1e12f : (float)(bv1 * bv1);

  *(float2*)&sA[w0] = make_float2(dv0, dv1);
  __syncthreads();

  // ---- horizontal min-plus: shared-window chunked scan ----
  float best0 = dv0, best1 = dv1;
  for (int o0 = 1; o0 < WW; o0 += 8) {   // o0 odd: windows are even-aligned
    if (__all((float)(o0 * o0) >= fmaxf(best0, best1))) break;
    const float2* Lp = (const float2*)&sA[w0 - o0 - 7];  // covers lb..lb+9
    const float2* Rp = (const float2*)&sA[w0 + o0 - 1];  // covers rb..rb+9
    float2 L0 = Lp[0], L1 = Lp[1], L2 = Lp[2], L3 = Lp[3], L4 = Lp[4];
    float2 R0 = Rp[0], R1 = Rp[1], R2 = Rp[2], R3 = Rp[3], R4 = Rp[4];
    // px0 (w0): left idx = lb + 7-u, right idx = rb + 1+u
    // px1 (w0+1): left idx = lb + 8-u, right idx = rb + 2+u
#define STEP(U, L0C, R0C, L1C, R1C)                         \
    { int o = o0 + (U); float oo = (float)(o * o);          \
      best0 = fminf(best0, fminf((L0C), (R0C)) + oo);       \
      best1 = fminf(best1, fminf((L1C), (R1C)) + oo); }
    STEP(0, L3.y, R0.y, L4.x, R1.x)
    STEP(1, L3.x, R1.x, L3.y, R1.y)
    STEP(2, L2.y, R1.y, L3.x, R2.x)
    STEP(3, L2.x, R2.x, L2.y, R2.y)
    STEP(4, L1.y, R2.y, L2.x, R3.x)
    STEP(5, L1.x, R3.x, L1.y, R3.y)
    STEP(6, L0.y, R3.y, L1.x, R4.x)
    STEP(7, L0.x, R4.x, L0.y, R4.y)
#undef STEP
  }

  // ---- loss terms ----
  float acc_p = 0.f, acc_t = 0.f, acc_pt = 0.f, acc_pen = 0.f;
  {
    float e = __expf(-xv.x);
    float p = __builtin_amdgcn_rcpf(1.f + e);
    float wgt = (best0 > 1e9f)
                    ? 0.f
                    : (1.f - __expf(-__builtin_amdgcn_sqrtf(best0) * 0.02f));
    acc_p += p; acc_t += tval0; acc_pt += p * tval0;
    acc_pen += wgt * p * (1.f - tval0);
  }
  {
    float e = __expf(-xv.y);
    float p = __builtin_amdgcn_rcpf(1.f + e);
    float wgt = (best1 > 1e9f)
                    ? 0.f
                    : (1.f - __expf(-__builtin_amdgcn_sqrtf(best1) * 0.02f));
    acc_p += p; acc_t += tval1; acc_pt += p * tval1;
    acc_pen += wgt * p * (1.f - tval1);
  }

  // wave(64) shuffle reduce, then across the 4 waves via LDS
  #pragma unroll
  for (int off = 32; off; off >>= 1) {
    acc_p  += __shfl_down(acc_p,  off);
    acc_t  += __shfl_down(acc_t,  off);
    acc_pt += __shfl_down(acc_pt, off);
    acc_pen += __shfl_down(acc_pen, off);
  }
  int wave = tid >> 6, lane = tid & 63;
  if (lane == 0) {
    wsum[wave][0] = acc_p; wsum[wave][1] = acc_t;
    wsum[wave][2] = acc_pt; wsum[wave][3] = acc_pen;
  }
  __syncthreads();
  if (tid == 0) {
    float r0 = 0.f, r1 = 0.f, r2 = 0.f, r3 = 0.f;
    #pragma unroll
    for (int wv = 0; wv < 4; ++wv) {
      r0 += wsum[wv][0]; r1 += wsum[wv][1];
      r2 += wsum[wv][2]; r3 += wsum[wv][3];
    }
    partials[0 * NROWS + row] = r0;
    partials[1 * NROWS + row] = r1;
    partials[2 * NROWS + row] = r2;
    partials[3 * NROWS + row] = r3;
  }
}

// ---------------------------------------------------------------------------
// Kernel C: deterministic final reduce of 8192x4 partials + scalar loss.
// ---------------------------------------------------------------------------
__global__ __launch_bounds__(256) void finalize_kernel(
    const float* __restrict__ partials, float* __restrict__ out) {
  __shared__ float wsum[4][4];
  int tid = threadIdx.x;
  float a0 = 0.f, a1 = 0.f, a2 = 0.f, a3 = 0.f;
  for (int k = tid; k < NROWS; k += 256) {
    a0 += partials[0 * NROWS + k];
    a1 += partials[1 * NROWS + k];
    a2 += partials[2 * NROWS + k];
    a3 += partials[3 * NROWS + k];
  }
  #pragma unroll
  for (int off = 32; off; off >>= 1) {
    a0 += __shfl_down(a0, off);
    a1 += __shfl_down(a1, off);
    a2 += __shfl_down(a2, off);
    a3 += __shfl_down(a3, off);
  }
  int wave = tid >> 6, lane = tid & 63;
  if (lane == 0) {
    wsum[wave][0] = a0; wsum[wave][1] = a1;
    wsum[wave][2] = a2; wsum[wave][3] = a3;
  }
  __syncthreads();
  if (tid == 0) {
    float sp = 0.f, st = 0.f, inter = 0.f, pen = 0.f;
    #pragma unroll
    for (int wv = 0; wv < 4; ++wv) {
      sp += wsum[wv][0]; st += wsum[wv][1];
      inter += wsum[wv][2]; pen += wsum[wv][3];
    }
    float uni = sp + st - inter;
    float iou_loss = 1.f - (inter + 1e-6f) / (uni + 1e-6f);
    float penalty = pen / (float)NPIX;
    out[0] = iou_loss + 0.5f * penalty;
  }
}

extern "C" void kernel_launch(void* const* d_in, const int* in_sizes, int n_in,
                              void* d_out, int out_size, void* d_ws, size_t ws_size,
                              hipStream_t stream) {
  const float* logits = (const float*)d_in[0];
  const float* tg     = (const float*)d_in[1];
  char* base = (char*)d_ws;
  unsigned int* mask = (unsigned int*)base;               // 512 KB
  short* un_s = (short*)(base + 524288);                  // 16*17*512 shorts
  short* dn_s = (short*)(base + 802816);
  float* partials = (float*)(base + 1081344);             // 128 KB
  float* out = (float*)d_out;

  hipLaunchKernelGGL(build_kernel, dim3(BB * 16), dim3(512), 0, stream,
                     tg, mask, un_s, dn_s);
  hipLaunchKernelGGL(rows_loss_kernel, dim3(NROWS), dim3(256), 0, stream,
                     logits, mask, un_s, dn_s, partials);
  hipLaunchKernelGGL(finalize_kernel, dim3(1), dim3(256), 0, stream,
                     partials, out);
}

// Round 10
// 27.496 us; speedup vs baseline: 7.5103x; 1.4000x over previous
//
#include <hip/hip_runtime.h>
#include <math.h>

// Problem constants (B=16, H=512, W=512, fp32 in/out)
#define BB 16
#define HH 512
#define WW 512
#define NPIX (BB*HH*WW)   // 4194304
#define NWORDS 16         // 512 rows / 32 bits (full res)
#define HB 256            // half-res grid 256x256
#define HWORDS 8          // 256 block-rows / 32
#define NBLK_C 4096       // loss-pass blocks

// extract even bits 0,2,4,..,30 of x into low 16 bits
__device__ inline unsigned int even16(unsigned int x) {
  x &= 0x55555555u;
  x = (x | (x >> 1)) & 0x33333333u;
  x = (x | (x >> 2)) & 0x0F0F0F0Fu;
  x = (x | (x >> 4)) & 0x00FF00FFu;
  x = (x | (x >> 8)) & 0x0000FFFFu;
  return x;
}

// ---------------------------------------------------------------------------
// Kernel A: full-res column bitmasks (for exact t bit-tests) + 2x2-downsampled
// half-res column bitmasks + half-res nearest-set-bit tables.
//   hmask[b][kp][bc] bit r = any fg in px rows 64kp+2r..64kp+2r+1,
//                            px cols 2bc..2bc+1       (kp<8, bc<256)
//   un_h[b][kp][bc]   = first set block-row >= 32kp   (slot 8 = +16000)
//   dn_h[b][kp+1][bc] = last  set block-row <= 32kp+31 (slot 0 = -16000)
// No atomics, no fences.
// ---------------------------------------------------------------------------
__global__ __launch_bounds__(512) void build_kernel(
    const float* __restrict__ tg, unsigned int* __restrict__ mask,
    unsigned int* __restrict__ hmask, short* __restrict__ un_h,
    short* __restrict__ dn_h) {
  __shared__ unsigned int smask[NWORDS][32];
  __shared__ unsigned int hsm[HWORDS][16];
  int wt = blockIdx.x & 15;          // 16 col-tiles of 32
  int b  = blockIdx.x >> 4;
  int c  = threadIdx.x & 31;
  int k  = threadIdx.x >> 5;         // 0..15
  int w  = (wt << 5) + c;
  const float* p = tg + ((size_t)(b * HH + (k << 5))) * WW + w;
  unsigned int word = 0;
  #pragma unroll
  for (int r = 0; r < 32; ++r)
    word |= (p[(size_t)r * WW] > 0.f ? 1u : 0u) << r;
  smask[k][c] = word;
  mask[(b * NWORDS + k) * WW + w] = word;
  __syncthreads();
  int t = threadIdx.x;
  if (t < 128) {                     // half-res pack: 8 words x 16 block-cols
    int kp  = t >> 4;                // 0..7
    int bcl = t & 15;                // 0..15
    unsigned int wa = smask[2 * kp][2 * bcl] | smask[2 * kp][2 * bcl + 1];
    unsigned int wb = smask[2 * kp + 1][2 * bcl] | smask[2 * kp + 1][2 * bcl + 1];
    unsigned int hword = even16(wa | (wa >> 1)) | (even16(wb | (wb >> 1)) << 16);
    hsm[kp][bcl] = hword;
    hmask[(b * HWORDS + kp) * HB + (wt << 4) + bcl] = hword;
  }
  __syncthreads();
  if (t < 16) {                      // suffix scan: first set block-row >= 32kp
    int bc = (wt << 4) + t;
    int cur = 16000;
    un_h[(b * 9 + 8) * HB + bc] = (short)cur;
    #pragma unroll
    for (int kp = HWORDS - 1; kp >= 0; --kp) {
      unsigned int m = hsm[kp][t];
      if (m) cur = (kp << 5) + (int)__builtin_ctz(m);
      un_h[(b * 9 + kp) * HB + bc] = (short)cur;
    }
  } else if (t >= 64 && t < 80) {    // prefix scan: last set block-row <= 32kp+31
    int tt = t - 64;
    int bc = (wt << 4) + tt;
    int cur = -16000;
    dn_h[(b * 9 + 0) * HB + bc] = (short)cur;
    #pragma unroll
    for (int kp = 0; kp < HWORDS; ++kp) {
      unsigned int m = hsm[kp][tt];
      if (m) cur = (kp << 5) + 31 - (int)__builtin_clz(m);
      dn_h[(b * 9 + kp + 1) * HB + bc] = (short)cur;
    }
  }
}

// ---------------------------------------------------------------------------
// Kernel B: half-res EDT (vertical O(1) from tables + horizontal min-plus
// with the R9-proven shared-window chunked scan) -> weight grid.
// One block per (b, block-row R); 128 threads own adjacent cols {2t, 2t+1}.
// Physical distance = 2*sqrt(best) block units -> w = 1-exp(-sqrt(best)*2/50).
// ---------------------------------------------------------------------------
__global__ __launch_bounds__(128) void edt_half_kernel(
    const unsigned int* __restrict__ hmask, const short* __restrict__ un_h,
    const short* __restrict__ dn_h, float* __restrict__ wgrid) {
  __shared__ __align__(16) float sraw[256 + HB + 256];
  float* sA = sraw + 256;

  int blk = blockIdx.x;             // b*256 + R
  int b = blk >> 8, R = blk & 255;
  int tid = threadIdx.x;            // 0..127
  int C0 = tid << 1;

  // pads (never allowed to win the min)
  *(float2*)&sraw[C0] = make_float2(3e12f, 3e12f);
  *(float2*)&sraw[512 + C0] = make_float2(3e12f, 3e12f);

  int k0 = R >> 5, pos = R & 31;    // block-uniform
  unsigned int pmask_lo = (1u << pos) - 1u;
  unsigned int pmask_le = pmask_lo | (1u << pos);

  uint2 m2 = *(const uint2*)&hmask[(b * HWORDS + k0) * HB + C0];
  int un2 = *(const int*)&un_h[(b * 9 + k0 + 1) * HB + C0];
  int dn2 = *(const int*)&dn_h[(b * 9 + k0) * HB + C0];

  // vertical EDT px0
  unsigned int upm0  = m2.x & ~pmask_lo;
  unsigned int lowm0 = m2.x & pmask_le;
  int up0  = upm0  ? ((k0 << 5) + (int)__builtin_ctz(upm0))       : (int)(short)(un2 & 0xffff);
  int dnv0 = lowm0 ? ((k0 << 5) + 31 - (int)__builtin_clz(lowm0)) : (int)(short)(dn2 & 0xffff);
  int bv0 = min(up0 - R, R - dnv0);
  float dv0 = (bv0 > 255) ? 1e12f : (float)(bv0 * bv0);
  // vertical EDT px1
  unsigned int upm1  = m2.y & ~pmask_lo;
  unsigned int lowm1 = m2.y & pmask_le;
  int up1  = upm1  ? ((k0 << 5) + (int)__builtin_ctz(upm1))       : (int)(short)(un2 >> 16);
  int dnv1 = lowm1 ? ((k0 << 5) + 31 - (int)__builtin_clz(lowm1)) : (int)(short)(dn2 >> 16);
  int bv1 = min(up1 - R, R - dnv1);
  float dv1 = (bv1 > 255) ? 1e12f : (float)(bv1 * bv1);

  *(float2*)&sA[C0] = make_float2(dv0, dv1);
  __syncthreads();

  // horizontal min-plus: shared-window chunked scan (R9-proven mapping)
  float best0 = dv0, best1 = dv1;
  for (int o0 = 1; o0 < HB; o0 += 8) {   // o0 odd: windows even-aligned
    if (__all((float)(o0 * o0) >= fmaxf(best0, best1))) break;
    const float2* Lp = (const float2*)&sA[C0 - o0 - 7];
    const float2* Rp = (const float2*)&sA[C0 + o0 - 1];
    float2 L0 = Lp[0], L1 = Lp[1], L2 = Lp[2], L3 = Lp[3], L4 = Lp[4];
    float2 R0 = Rp[0], R1 = Rp[1], R2 = Rp[2], R3 = Rp[3], R4 = Rp[4];
#define STEP(U, L0C, R0C, L1C, R1C)                         \
    { int o = o0 + (U); float oo = (float)(o * o);          \
      best0 = fminf(best0, fminf((L0C), (R0C)) + oo);       \
      best1 = fminf(best1, fminf((L1C), (R1C)) + oo); }
    STEP(0, L3.y, R0.y, L4.x, R1.x)
    STEP(1, L3.x, R1.x, L3.y, R1.y)
    STEP(2, L2.y, R1.y, L3.x, R2.x)
    STEP(3, L2.x, R2.x, L2.y, R2.y)
    STEP(4, L1.y, R2.y, L2.x, R3.x)
    STEP(5, L1.x, R3.x, L1.y, R3.y)
    STEP(6, L0.y, R3.y, L1.x, R4.x)
    STEP(7, L0.x, R4.x, L0.y, R4.y)
#undef STEP
  }

  // weight: physical d = 2*sqrt(best_blk); empty sample -> 0 (has_fg)
  float w0 = (best0 > 1e9f)
                 ? 0.f
                 : (1.f - __expf(-__builtin_amdgcn_sqrtf(best0) * 0.04f));
  float w1 = (best1 > 1e9f)
                 ? 0.f
                 : (1.f - __expf(-__builtin_amdgcn_sqrtf(best1) * 0.04f));
  *(float2*)&wgrid[(b * HB + R) * HB + C0] = make_float2(w0, w1);
}

// ---------------------------------------------------------------------------
// Kernel C: per-pixel loss pass. Thread owns 4 consecutive px of one row:
// float4 logits, uint4 mask words (t = bit test), float2 half-res weights
// (each serves 2 px). Accumulate {p, t, p*t, w*p*(1-t)} -> block partials.
// ---------------------------------------------------------------------------
__global__ __launch_bounds__(256) void loss_kernel(
    const float* __restrict__ logits, const unsigned int* __restrict__ mask,
    const float* __restrict__ wgrid, float* __restrict__ partials) {
  __shared__ float wsum[4][4];
  int tid = threadIdx.x;
  int g = blockIdx.x * 256 + tid;          // 0 .. 1048575
  int b = g >> 16, rem = g & 65535;
  int i = rem >> 7, w0 = (rem & 127) << 2;

  float4 x4 = *(const float4*)&logits[((size_t)(b * HH + i)) * WW + w0];
  uint4 mw = *(const uint4*)&mask[(b * NWORDS + (i >> 5)) * WW + w0];
  float2 wv = *(const float2*)&wgrid[(b * HB + (i >> 1)) * HB + (w0 >> 1)];
  int bit = i & 31;

  float acc_p = 0.f, acc_t = 0.f, acc_pt = 0.f, acc_pen = 0.f;
#define PX(XC, WC, MC)                                      \
  { float x = (XC);                                         \
    float tt = (float)(((MC) >> bit) & 1u);                 \
    float e = __expf(-x);                                   \
    float pp = __builtin_amdgcn_rcpf(1.f + e);              \
    acc_p += pp; acc_t += tt; acc_pt += pp * tt;            \
    acc_pen += (WC) * pp * (1.f - tt); }
  PX(x4.x, wv.x, mw.x)
  PX(x4.y, wv.x, mw.y)
  PX(x4.z, wv.y, mw.z)
  PX(x4.w, wv.y, mw.w)
#undef PX

  #pragma unroll
  for (int off = 32; off; off >>= 1) {
    acc_p  += __shfl_down(acc_p,  off);
    acc_t  += __shfl_down(acc_t,  off);
    acc_pt += __shfl_down(acc_pt, off);
    acc_pen += __shfl_down(acc_pen, off);
  }
  int wave = tid >> 6, lane = tid & 63;
  if (lane == 0) {
    wsum[wave][0] = acc_p; wsum[wave][1] = acc_t;
    wsum[wave][2] = acc_pt; wsum[wave][3] = acc_pen;
  }
  __syncthreads();
  if (tid == 0) {
    float r0 = 0.f, r1 = 0.f, r2 = 0.f, r3 = 0.f;
    #pragma unroll
    for (int wv2 = 0; wv2 < 4; ++wv2) {
      r0 += wsum[wv2][0]; r1 += wsum[wv2][1];
      r2 += wsum[wv2][2]; r3 += wsum[wv2][3];
    }
    partials[0 * NBLK_C + blockIdx.x] = r0;
    partials[1 * NBLK_C + blockIdx.x] = r1;
    partials[2 * NBLK_C + blockIdx.x] = r2;
    partials[3 * NBLK_C + blockIdx.x] = r3;
  }
}

// ---------------------------------------------------------------------------
// Kernel D: deterministic final reduce of 4096x4 partials + scalar loss.
// ---------------------------------------------------------------------------
__global__ __launch_bounds__(256) void finalize_kernel(
    const float* __restrict__ partials, float* __restrict__ out) {
  __shared__ float wsum[4][4];
  int tid = threadIdx.x;
  float a0 = 0.f, a1 = 0.f, a2 = 0.f, a3 = 0.f;
  for (int k = tid; k < NBLK_C; k += 256) {
    a0 += partials[0 * NBLK_C + k];
    a1 += partials[1 * NBLK_C + k];
    a2 += partials[2 * NBLK_C + k];
    a3 += partials[3 * NBLK_C + k];
  }
  #pragma unroll
  for (int off = 32; off; off >>= 1) {
    a0 += __shfl_down(a0, off);
    a1 += __shfl_down(a1, off);
    a2 += __shfl_down(a2, off);
    a3 += __shfl_down(a3, off);
  }
  int wave = tid >> 6, lane = tid & 63;
  if (lane == 0) {
    wsum[wave][0] = a0; wsum[wave][1] = a1;
    wsum[wave][2] = a2; wsum[wave][3] = a3;
  }
  __syncthreads();
  if (tid == 0) {
    float sp = 0.f, st = 0.f, inter = 0.f, pen = 0.f;
    #pragma unroll
    for (int wv = 0; wv < 4; ++wv) {
      sp += wsum[wv][0]; st += wsum[wv][1];
      inter += wsum[wv][2]; pen += wsum[wv][3];
    }
    float uni = sp + st - inter;
    float iou_loss = 1.f - (inter + 1e-6f) / (uni + 1e-6f);
    float penalty = pen / (float)NPIX;
    out[0] = iou_loss + 0.5f * penalty;
  }
}

extern "C" void kernel_launch(void* const* d_in, const int* in_sizes, int n_in,
                              void* d_out, int out_size, void* d_ws, size_t ws_size,
                              hipStream_t stream) {
  const float* logits = (const float*)d_in[0];
  const float* tg     = (const float*)d_in[1];
  char* base = (char*)d_ws;
  unsigned int* mask  = (unsigned int*)base;                 // 512 KB
  unsigned int* hmask = (unsigned int*)(base + 524288);      // 16*8*256*4 = 128 KB
  short* un_h = (short*)(base + 655360);                     // 16*9*256*2 = 72 KB
  short* dn_h = (short*)(base + 729088);                     // 72 KB
  float* wgrid = (float*)(base + 802816);                    // 4 MB
  float* partials = (float*)(base + 4997120);                // 64 KB
  float* out = (float*)d_out;

  hipLaunchKernelGGL(build_kernel, dim3(BB * 16), dim3(512), 0, stream,
                     tg, mask, hmask, un_h, dn_h);
  hipLaunchKernelGGL(edt_half_kernel, dim3(BB * HB), dim3(128), 0, stream,
                     hmask, un_h, dn_h, wgrid);
  hipLaunchKernelGGL(loss_kernel, dim3(NBLK_C), dim3(256), 0, stream,
                     logits, mask, wgrid, partials);
  hipLaunchKernelGGL(finalize_kernel, dim3(1), dim3(256), 0, stream,
                     partials, out);
}

// Round 11
// 25.353 us; speedup vs baseline: 8.1451x; 1.0845x over previous
//
#include <hip/hip_runtime.h>
#include <math.h>

// Problem constants (B=16, H=512, W=512, fp32 in/out)
#define BB 16
#define HH 512
#define WW 512
#define NPIX (BB*HH*WW)   // 4194304
#define NWORDS 16         // 512 rows / 32 bits (full res)
#define HB 256            // half-res grid 256x256
#define HWORDS 8          // 256 block-rows / 32
#define NBLK 4096         // fused-pass blocks = 16 * 256

// extract even bits 0,2,4,..,30 of x into low 16 bits
__device__ inline unsigned int even16(unsigned int x) {
  x &= 0x55555555u;
  x = (x | (x >> 1)) & 0x33333333u;
  x = (x | (x >> 2)) & 0x0F0F0F0Fu;
  x = (x | (x >> 4)) & 0x00FF00FFu;
  x = (x | (x >> 8)) & 0x0000FFFFu;
  return x;
}

// ---------------------------------------------------------------------------
// Kernel A: full-res column bitmasks (for exact t bit-tests) + 2x2-downsampled
// half-res column bitmasks + half-res nearest-set-bit tables.
//   hmask[b][kp][bc] bit r = any fg in px rows 64kp+2r..64kp+2r+1,
//                            px cols 2bc..2bc+1       (kp<8, bc<256)
//   un_h[b][kp][bc]   = first set block-row >= 32kp    (slot 8 = +16000)
//   dn_h[b][kp+1][bc] = last  set block-row <= 32kp+31 (slot 0 = -16000)
// No atomics, no fences.
// ---------------------------------------------------------------------------
__global__ __launch_bounds__(512) void build_kernel(
    const float* __restrict__ tg, unsigned int* __restrict__ mask,
    unsigned int* __restrict__ hmask, short* __restrict__ un_h,
    short* __restrict__ dn_h) {
  __shared__ unsigned int smask[NWORDS][32];
  __shared__ unsigned int hsm[HWORDS][16];
  int wt = blockIdx.x & 15;          // 16 col-tiles of 32
  int b  = blockIdx.x >> 4;
  int c  = threadIdx.x & 31;
  int k  = threadIdx.x >> 5;         // 0..15
  int w  = (wt << 5) + c;
  const float* p = tg + ((size_t)(b * HH + (k << 5))) * WW + w;
  unsigned int word = 0;
  #pragma unroll
  for (int r = 0; r < 32; ++r)
    word |= (p[(size_t)r * WW] > 0.f ? 1u : 0u) << r;
  smask[k][c] = word;
  mask[(b * NWORDS + k) * WW + w] = word;
  __syncthreads();
  int t = threadIdx.x;
  if (t < 128) {                     // half-res pack: 8 words x 16 block-cols
    int kp  = t >> 4;                // 0..7
    int bcl = t & 15;                // 0..15
    unsigned int wa = smask[2 * kp][2 * bcl] | smask[2 * kp][2 * bcl + 1];
    unsigned int wb = smask[2 * kp + 1][2 * bcl] | smask[2 * kp + 1][2 * bcl + 1];
    unsigned int hword = even16(wa | (wa >> 1)) | (even16(wb | (wb >> 1)) << 16);
    hsm[kp][bcl] = hword;
    hmask[(b * HWORDS + kp) * HB + (wt << 4) + bcl] = hword;
  }
  __syncthreads();
  if (t < 16) {                      // suffix scan: first set block-row >= 32kp
    int bc = (wt << 4) + t;
    int cur = 16000;
    un_h[(b * 9 + 8) * HB + bc] = (short)cur;
    #pragma unroll
    for (int kp = HWORDS - 1; kp >= 0; --kp) {
      unsigned int m = hsm[kp][t];
      if (m) cur = (kp << 5) + (int)__builtin_ctz(m);
      un_h[(b * 9 + kp) * HB + bc] = (short)cur;
    }
  } else if (t >= 64 && t < 80) {    // prefix scan: last set block-row <= 32kp+31
    int tt = t - 64;
    int bc = (wt << 4) + tt;
    int cur = -16000;
    dn_h[(b * 9 + 0) * HB + bc] = (short)cur;
    #pragma unroll
    for (int kp = 0; kp < HWORDS; ++kp) {
      unsigned int m = hsm[kp][tt];
      if (m) cur = (kp << 5) + 31 - (int)__builtin_clz(m);
      dn_h[(b * 9 + kp + 1) * HB + bc] = (short)cur;
    }
  }
}

// ---------------------------------------------------------------------------
// Kernel B (fused): half-res EDT for block-row R -> weights in LDS -> loss
// terms for the two full-res rows {2R, 2R+1}. One block per (b, R);
// 256 threads. Vertical EDT O(1)/col from tables; horizontal min-plus
// scalar stride-1 scan (1 col/thread, wave-uniform chunked early exit);
// loss: thread t owns row 2R+(t>>7), cols 4(t&127)..+3 (float4/uint4 loads,
// weight float2 from LDS serves 4 px). No atomics, no fences.
// ---------------------------------------------------------------------------
__global__ __launch_bounds__(256) void edt_loss_kernel(
    const float* __restrict__ logits, const unsigned int* __restrict__ mask,
    const unsigned int* __restrict__ hmask, const short* __restrict__ un_h,
    const short* __restrict__ dn_h, float* __restrict__ partials) {
  __shared__ __align__(16) float sraw[256 + HB + 256];
  __shared__ __align__(8) float sw[HB];
  __shared__ float wsum[4][4];
  float* sA = sraw + 256;

  int blk = blockIdx.x;             // b*256 + R
  int b = blk >> 8, R = blk & 255;
  int tid = threadIdx.x;            // 0..255, owns half-res column tid

  // pads (never allowed to win the min)
  sraw[tid] = 3e12f;
  sraw[256 + HB + tid] = 3e12f;

  int k0 = R >> 5, pos = R & 31;    // block-uniform
  unsigned int pmask_lo = (1u << pos) - 1u;
  unsigned int pmask_le = pmask_lo | (1u << pos);

  unsigned int m0 = hmask[(b * HWORDS + k0) * HB + tid];
  int un_next = un_h[(b * 9 + k0 + 1) * HB + tid];
  int dn_prev = dn_h[(b * 9 + k0) * HB + tid];

  unsigned int upm  = m0 & ~pmask_lo;
  unsigned int lowm = m0 & pmask_le;
  int up  = upm  ? ((k0 << 5) + (int)__builtin_ctz(upm))       : un_next;
  int dnv = lowm ? ((k0 << 5) + 31 - (int)__builtin_clz(lowm)) : dn_prev;
  int bv = min(up - R, R - dnv);
  float dv = (bv > 255) ? 1e12f : (float)(bv * bv);
  sA[tid] = dv;
  __syncthreads();

  // horizontal min-plus: scalar stride-1 chunked scan, wave-uniform exit
  float best = dv;
  for (int o0 = 1; o0 < HB; o0 += 8) {
    if (__all((float)(o0 * o0) >= best)) break;
    #pragma unroll
    for (int u = 0; u < 8; ++u) {
      int o = o0 + u;
      best = fminf(best, fminf(sA[tid - o], sA[tid + o]) + (float)(o * o));
    }
  }
  // weight: physical d = 2*sqrt(best_blk); empty sample -> 0 (has_fg)
  sw[tid] = (best > 1e9f)
                ? 0.f
                : (1.f - __expf(-__builtin_amdgcn_sqrtf(best) * 0.04f));
  __syncthreads();

  // ---- per-pixel loss on rows {2R, 2R+1} ----
  int i = (R << 1) + (tid >> 7);    // full-res row
  int w0 = (tid & 127) << 2;        // 4 consecutive columns
  float4 x4 = *(const float4*)&logits[((size_t)(b * HH + i)) * WW + w0];
  uint4 mw = *(const uint4*)&mask[(b * NWORDS + (i >> 5)) * WW + w0];
  float2 wv = *(const float2*)&sw[w0 >> 1];
  int bit = i & 31;

  float acc_p = 0.f, acc_t = 0.f, acc_pt = 0.f, acc_pen = 0.f;
#define PX(XC, WC, MC)                                      \
  { float x = (XC);                                         \
    float tt = (float)(((MC) >> bit) & 1u);                 \
    float e = __expf(-x);                                   \
    float pp = __builtin_amdgcn_rcpf(1.f + e);              \
    acc_p += pp; acc_t += tt; acc_pt += pp * tt;            \
    acc_pen += (WC) * pp * (1.f - tt); }
  PX(x4.x, wv.x, mw.x)
  PX(x4.y, wv.x, mw.y)
  PX(x4.z, wv.y, mw.z)
  PX(x4.w, wv.y, mw.w)
#undef PX

  #pragma unroll
  for (int off = 32; off; off >>= 1) {
    acc_p  += __shfl_down(acc_p,  off);
    acc_t  += __shfl_down(acc_t,  off);
    acc_pt += __shfl_down(acc_pt, off);
    acc_pen += __shfl_down(acc_pen, off);
  }
  int wave = tid >> 6, lane = tid & 63;
  if (lane == 0) {
    wsum[wave][0] = acc_p; wsum[wave][1] = acc_t;
    wsum[wave][2] = acc_pt; wsum[wave][3] = acc_pen;
  }
  __syncthreads();
  if (tid == 0) {
    float r0 = 0.f, r1 = 0.f, r2 = 0.f, r3 = 0.f;
    #pragma unroll
    for (int wv2 = 0; wv2 < 4; ++wv2) {
      r0 += wsum[wv2][0]; r1 += wsum[wv2][1];
      r2 += wsum[wv2][2]; r3 += wsum[wv2][3];
    }
    partials[0 * NBLK + blk] = r0;
    partials[1 * NBLK + blk] = r1;
    partials[2 * NBLK + blk] = r2;
    partials[3 * NBLK + blk] = r3;
  }
}

// ---------------------------------------------------------------------------
// Kernel C: deterministic final reduce of 4096x4 partials + scalar loss.
// ---------------------------------------------------------------------------
__global__ __launch_bounds__(256) void finalize_kernel(
    const float* __restrict__ partials, float* __restrict__ out) {
  __shared__ float wsum[4][4];
  int tid = threadIdx.x;
  float a0 = 0.f, a1 = 0.f, a2 = 0.f, a3 = 0.f;
  for (int k = tid; k < NBLK; k += 256) {
    a0 += partials[0 * NBLK + k];
    a1 += partials[1 * NBLK + k];
    a2 += partials[2 * NBLK + k];
    a3 += partials[3 * NBLK + k];
  }
  #pragma unroll
  for (int off = 32; off; off >>= 1) {
    a0 += __shfl_down(a0, off);
    a1 += __shfl_down(a1, off);
    a2 += __shfl_down(a2, off);
    a3 += __shfl_down(a3, off);
  }
  int wave = tid >> 6, lane = tid & 63;
  if (lane == 0) {
    wsum[wave][0] = a0; wsum[wave][1] = a1;
    wsum[wave][2] = a2; wsum[wave][3] = a3;
  }
  __syncthreads();
  if (tid == 0) {
    float sp = 0.f, st = 0.f, inter = 0.f, pen = 0.f;
    #pragma unroll
    for (int wv = 0; wv < 4; ++wv) {
      sp += wsum[wv][0]; st += wsum[wv][1];
      inter += wsum[wv][2]; pen += wsum[wv][3];
    }
    float uni = sp + st - inter;
    float iou_loss = 1.f - (inter + 1e-6f) / (uni + 1e-6f);
    float penalty = pen / (float)NPIX;
    out[0] = iou_loss + 0.5f * penalty;
  }
}

extern "C" void kernel_launch(void* const* d_in, const int* in_sizes, int n_in,
                              void* d_out, int out_size, void* d_ws, size_t ws_size,
                              hipStream_t stream) {
  const float* logits = (const float*)d_in[0];
  const float* tg     = (const float*)d_in[1];
  char* base = (char*)d_ws;
  unsigned int* mask  = (unsigned int*)base;                 // 512 KB
  unsigned int* hmask = (unsigned int*)(base + 524288);      // 128 KB
  short* un_h = (short*)(base + 655360);                     // 72 KB
  short* dn_h = (short*)(base + 729088);                     // 72 KB
  float* partials = (float*)(base + 802816);                 // 64 KB
  float* out = (float*)d_out;

  hipLaunchKernelGGL(build_kernel, dim3(BB * 16), dim3(512), 0, stream,
                     tg, mask, hmask, un_h, dn_h);
  hipLaunchKernelGGL(edt_loss_kernel, dim3(NBLK), dim3(256), 0, stream,
                     logits, mask, hmask, un_h, dn_h, partials);
  hipLaunchKernelGGL(finalize_kernel, dim3(1), dim3(256), 0, stream,
                     partials, out);
}